// Round 10
// baseline (949.571 us; speedup 1.0000x reference)
//
#include <hip/hip_runtime.h>
#include <hip/hip_bf16.h>
#include <hip/hip_cooperative_groups.h>

namespace cg = cooperative_groups;

// DimeNet-like GNN, f32 in/out (flag=1 confirmed rounds 2-8; ws ~268 MB).
// Round 9: ONE cooperative kernel, grid-synced phases. agg_e lives in
// registers (tri-bucket j and edge-bucket j handled by the same wave, with
// the Ad shfl-GEMV in between); G1 phase does Hh/Hs/Z0 in one pass over h;
// node phase adds aggr@Wn1b to Z0 and applies Wn2 via wave-private LDS
// transpose. 14 grid syncs replace 17 dispatches.

#define N_NODES 16000
#define N_EDGES 256000
#define N_TRI   640000
#define N_B     128
#define OUT_DIM 32
#define L_LAYERS 3

typedef __hip_bfloat16 bf16;
typedef short s8v __attribute__((ext_vector_type(8)));
typedef float f4v __attribute__((ext_vector_type(4)));

__device__ __forceinline__ float ldx(const void* p, size_t i, int f) {
    if (f) return ((const float*)p)[i];
    return __bfloat162float(((const bf16*)p)[i]);
}

__device__ __forceinline__ unsigned short f2bf_rne(float x) {
    unsigned int u = __float_as_uint(x);
    unsigned int r = (u + 0x7FFFu + ((u >> 16) & 1u)) >> 16;
    return (unsigned short)r;
}
__device__ __forceinline__ float bf2f(unsigned short b) {
    return __uint_as_float(((unsigned int)b) << 16);
}
__device__ __forceinline__ void split2(float a, unsigned short& h, unsigned short& l) {
    h = f2bf_rne(a);
    l = f2bf_rne(a - bf2f(h));
}
__device__ __forceinline__ void make_afrag(const float* av, s8v& ah, s8v& al) {
    #pragma unroll
    for (int j = 0; j < 8; j++) {
        unsigned short h, l; split2(av[j], h, l);
        ah[j] = (short)h; al[j] = (short)l;
    }
}

// stage a 64x64 weight block (K=64 -> 2 K-steps) into split hi/lo frag order
__device__ __forceinline__ void stageW64(const void* W, size_t offW, int f,
                                         unsigned short* hi, unsigned short* lo) {
    for (int idx = threadIdx.x; idx < 4096; idx += 256) {
        int jj = idx & 7, ln = (idx >> 3) & 63, nt = (idx >> 9) & 3, ks = idx >> 11;
        int k = ks * 32 + (ln >> 4) * 8 + jj;
        int n = nt * 16 + (ln & 15);
        float w = ldx(W, offW + (size_t)k * 64 + n, f);
        unsigned short h_, l_; split2(w, h_, l_);
        hi[idx] = h_; lo[idx] = l_;
    }
}

__device__ __forceinline__ void mfma3(const unsigned short* hi, const unsigned short* lo,
                                      int ks, int lane, const s8v& ah, const s8v& al,
                                      f4v acc[4]) {
    #pragma unroll
    for (int nt = 0; nt < 4; nt++) {
        s8v bh = *(const s8v*)&hi[(ks * 4 + nt) * 512 + lane * 8];
        s8v bl = *(const s8v*)&lo[(ks * 4 + nt) * 512 + lane * 8];
        acc[nt] = __builtin_amdgcn_mfma_f32_16x16x32_bf16(ah, bh, acc[nt], 0, 0, 0);
        acc[nt] = __builtin_amdgcn_mfma_f32_16x16x32_bf16(al, bh, acc[nt], 0, 0, 0);
        acc[nt] = __builtin_amdgcn_mfma_f32_16x16x32_bf16(ah, bl, acc[nt], 0, 0, 0);
    }
}

__device__ __forceinline__ void ldrow8(const void* A, int fa, size_t row, int ks,
                                       int quad, float av[8]) {
    if (fa) {
        const float* p = (const float*)A + row * 64 + ks * 32 + quad * 8;
        float4 x0 = ((const float4*)p)[0], x1 = ((const float4*)p)[1];
        av[0] = x0.x; av[1] = x0.y; av[2] = x0.z; av[3] = x0.w;
        av[4] = x1.x; av[5] = x1.y; av[6] = x1.z; av[7] = x1.w;
    } else {
        const bf16* p = (const bf16*)A + row * 64 + ks * 32 + quad * 8;
        #pragma unroll
        for (int j = 0; j < 8; j++) av[j] = __bfloat162float(p[j]);
    }
}

// ---------------------------------------------------------------- diag helpers
__global__ void k_probe(const void* __restrict__ rbf, int* __restrict__ flag) {
    if (threadIdx.x == 0 && blockIdx.x == 0) {
        const float* p = (const float*)rbf;
        int good = 0;
        for (int i = 0; i < 256; i++) {
            float v = fabsf(p[i]);
            if (v > 1e-4f && v < 100.0f) good++;
        }
        *flag = (good > 192) ? 1 : 0;
    }
}
__global__ void k_fill(void* __restrict__ out, const int* __restrict__ flag,
                       float val, int n) {
    int i = blockIdx.x * blockDim.x + threadIdx.x;
    if (i < n) {
        if (*flag) ((float*)out)[i] = val;
        else       ((bf16*)out)[i] = __float2bfloat16(val);
    }
}

// ---------------------------------------------------------------- mega kernel
struct MP {
    const void *x, *rbf, *cbf, *W1, *b1, *W2, *b2, *Wn1, *bn1, *Wn2, *bn2;
    const void *Wo1, *bo1, *Wo2, *bo2;
    const int *edge_index, *k_idx, *j_idx, *batch;
    float *h, *X, *Y, *Z0, *aggr;
    int *flag, *cur_t, *cur_e, *k_srt, *src_s;
    float *cbf_s;
    void *out;
};

__global__ __launch_bounds__(256, 2) void k_mega(MP p) {
    cg::grid_group gg = cg::this_grid();
    __shared__ __align__(16) unsigned char arena[53248];  // 52 KB, reused per phase
    const int tid = threadIdx.x;
    const int lane = tid & 63;
    const int w = tid >> 6;
    const int quad = lane >> 4;
    const int m = lane & 15;
    const int gwave = blockIdx.x * 4 + w;
    const int nwaves = gridDim.x * 4;
    const int gthr = blockIdx.x * 256 + tid;
    const int nthr = gridDim.x * 256;

    // ---- P0: zero cursors (cur_t,cur_e contiguous) + dtype probe ----
    for (int i = gthr; i < 2 * N_NODES; i += nthr) p.cur_t[i] = 0;
    if (gthr == 0) {
        const float* pr = (const float*)p.rbf;
        int good = 0;
        for (int q = 0; q < 256; q++) {
            float v = fabsf(pr[q]);
            if (v > 1e-4f && v < 100.0f) good++;
        }
        *p.flag = (good > 192) ? 1 : 0;
    }
    gg.sync();
    const int f = *p.flag;

    // ---- P1: histograms ----
    for (int i = gthr; i < N_TRI; i += nthr) {
        unsigned j = (unsigned)p.j_idx[i];
        if (j < N_NODES) atomicAdd(&p.cur_t[j], 1);
    }
    for (int i = gthr; i < N_EDGES; i += nthr) {
        unsigned d = (unsigned)p.edge_index[N_EDGES + i];
        if (d < N_NODES) atomicAdd(&p.cur_e[d], 1);
    }
    gg.sync();

    // ---- P2: exclusive scans (blocks 0,1) ----
    if (blockIdx.x < 2) {
        int* cnt = (blockIdx.x == 0) ? p.cur_t : p.cur_e;
        int* part = (int*)arena;
        const int PER = (N_NODES + 255) / 256;  // 63
        int base = tid * PER;
        int s = 0;
        for (int i = 0; i < PER; i++) {
            int idx = base + i;
            if (idx < N_NODES) s += cnt[idx];
        }
        part[tid] = s;
        __syncthreads();
        for (int d = 1; d < 256; d <<= 1) {
            int v = (tid >= d) ? part[tid - d] : 0;
            __syncthreads();
            part[tid] += v;
            __syncthreads();
        }
        int run = (tid > 0) ? part[tid - 1] : 0;
        for (int i = 0; i < PER; i++) {
            int idx = base + i;
            if (idx < N_NODES) {
                int v = cnt[idx];
                cnt[idx] = run;
                run += v;
            }
        }
    }
    gg.sync();

    // ---- P3: scatter + payload gather (cursors become bucket ends) ----
    for (int i = gthr; i < N_TRI; i += nthr) {
        unsigned j = (unsigned)p.j_idx[i];
        if (j < N_NODES) {
            int pos = atomicAdd(&p.cur_t[j], 1);
            if ((unsigned)pos < (unsigned)N_TRI) {
                unsigned k = (unsigned)p.k_idx[i]; if (k >= N_NODES) k = 0;
                p.k_srt[pos] = (int)k;
                #pragma unroll
                for (int q = 0; q < 6; q++)
                    p.cbf_s[(size_t)pos * 6 + q] = ldx(p.cbf, (size_t)i * 6 + q, f);
            }
        }
    }
    for (int e = gthr; e < N_EDGES; e += nthr) {
        unsigned d = (unsigned)p.edge_index[N_EDGES + e];
        if (d < N_NODES) {
            int pos = atomicAdd(&p.cur_e[d], 1);
            if ((unsigned)pos < (unsigned)N_EDGES) {
                unsigned s = (unsigned)p.edge_index[e]; if (s >= N_NODES) s = 0;
                p.src_s[pos] = (int)s;
            }
        }
    }
    gg.sync();

    // ---- layers ----
    for (int l = 0; l < L_LAYERS; l++) {
        const size_t offW1 = (size_t)l * 76 * 64;
        const size_t offW2 = (size_t)l * 128 * 64;
        const size_t offWn1 = (size_t)l * 128 * 64;
        const size_t offWn2 = (size_t)l * 64 * 64;
        const size_t offB = (size_t)l * 64;
        const void* A = (l == 0) ? p.x : (const void*)p.h;
        const int fa = (l == 0) ? f : 1;

        // -- G1: X=h@W1h+b1, Y=h@W2h+b2, Z0=h@Wn1a+bn1 (one pass over h) --
        {
            unsigned short* w1h = (unsigned short*)arena;
            unsigned short* w1l = (unsigned short*)(arena + 8192);
            unsigned short* w2h = (unsigned short*)(arena + 16384);
            unsigned short* w2l = (unsigned short*)(arena + 24576);
            unsigned short* w3h = (unsigned short*)(arena + 32768);
            unsigned short* w3l = (unsigned short*)(arena + 40960);
            float* sb1 = (float*)(arena + 49152);
            float* sb2 = (float*)(arena + 49408);
            float* sb3 = (float*)(arena + 49664);
            stageW64(p.W1, offW1, f, w1h, w1l);
            stageW64(p.W2, offW2, f, w2h, w2l);
            stageW64(p.Wn1, offWn1, f, w3h, w3l);
            if (tid < 64) {
                sb1[tid] = ldx(p.b1, offB + tid, f);
                sb2[tid] = ldx(p.b2, offB + tid, f);
                sb3[tid] = ldx(p.bn1, offB + tid, f);
            }
            __syncthreads();
            for (int tile = gwave; tile < N_NODES / 16; tile += nwaves) {
                size_t row = (size_t)tile * 16 + m;
                f4v aH[4], aS[4], aZ[4];
                #pragma unroll
                for (int nt = 0; nt < 4; nt++) {
                    float b1v = sb1[nt * 16 + m], b2v = sb2[nt * 16 + m], b3v = sb3[nt * 16 + m];
                    aH[nt] = (f4v){b1v, b1v, b1v, b1v};
                    aS[nt] = (f4v){b2v, b2v, b2v, b2v};
                    aZ[nt] = (f4v){b3v, b3v, b3v, b3v};
                }
                float av[8]; s8v ah, al;
                #pragma unroll
                for (int ks = 0; ks < 2; ks++) {
                    ldrow8(A, fa, row, ks, quad, av);
                    make_afrag(av, ah, al);
                    mfma3(w1h, w1l, ks, lane, ah, al, aH);
                    mfma3(w2h, w2l, ks, lane, ah, al, aS);
                    mfma3(w3h, w3l, ks, lane, ah, al, aZ);
                }
                #pragma unroll
                for (int r = 0; r < 4; r++) {
                    size_t rr = (size_t)(tile * 16 + quad * 4 + r) * 64 + m;
                    #pragma unroll
                    for (int nt = 0; nt < 4; nt++) {
                        p.X[rr + nt * 16] = aH[nt][r];
                        p.Y[rr + nt * 16] = aS[nt][r];
                        p.Z0[rr + nt * 16] = aZ[nt][r];
                    }
                }
            }
        }
        gg.sync();

        // -- TriEdge: per bucket j, agg row in registers, Ad via shfl-GEMV,
        //    then edge bucket j -> aggr[j]. No agg_e in memory. --
        {
            float* sW = (float*)arena;  // 64x64 W2a, 16 KB
            for (int idx = tid; idx < 4096; idx += 256)
                sW[idx] = ldx(p.W2, offW2 + 4096 + idx, f);
            __syncthreads();
            const int c = lane;
            float wr[6], wc[6];
            #pragma unroll
            for (int q = 0; q < 6; q++) {
                wr[q] = ldx(p.W1, offW1 + (size_t)(64 + q) * 64 + c, f);
                wc[q] = ldx(p.W1, offW1 + (size_t)(70 + q) * 64 + c, f);
            }
            for (int j = gwave; j < N_NODES; j += nwaves) {
                int p0 = (j == 0) ? 0 : p.cur_t[j - 1];
                int p1 = p.cur_t[j];
                if (p0 < 0) p0 = 0; if (p0 > N_TRI) p0 = N_TRI;
                if (p1 < p0) p1 = p0; if (p1 > N_TRI) p1 = N_TRI;
                float rb = 0.f;
                #pragma unroll
                for (int q = 0; q < 6; q++)
                    rb += ldx(p.rbf, (size_t)j * 6 + q, f) * wr[q];
                float s = 0.f;
                for (int q0 = p0; q0 < p1; q0 += 8) {
                    int kk[8]; float hv[8];
                    #pragma unroll
                    for (int i = 0; i < 8; i++) {
                        int k = (q0 + i < p1) ? p.k_srt[q0 + i] : 0;
                        if ((unsigned)k >= N_NODES) k = 0;
                        kk[i] = k;
                    }
                    #pragma unroll
                    for (int i = 0; i < 8; i++)
                        hv[i] = p.X[(size_t)kk[i] * 64 + c];
                    #pragma unroll
                    for (int i = 0; i < 8; i++) {
                        if (q0 + i >= p1) continue;
                        float v = hv[i] + rb;
                        #pragma unroll
                        for (int q = 0; q < 6; q++)
                            v += p.cbf_s[(size_t)(q0 + i) * 6 + q] * wc[q];
                        s += fmaxf(v, 0.f);
                    }
                }
                // Ad[j] = agg_row @ W2a  (f32 shfl-GEMV)
                float adv = 0.f;
                #pragma unroll
                for (int k = 0; k < 64; k++)
                    adv += __shfl(s, k) * sW[k * 64 + c];
                // edge bucket j
                int e0 = (j == 0) ? 0 : p.cur_e[j - 1];
                int e1 = p.cur_e[j];
                if (e0 < 0) e0 = 0; if (e0 > N_EDGES) e0 = N_EDGES;
                if (e1 < e0) e1 = e0; if (e1 > N_EDGES) e1 = N_EDGES;
                float s2 = 0.f;
                for (int q0 = e0; q0 < e1; q0 += 8) {
                    int ss[8]; float hv[8];
                    #pragma unroll
                    for (int i = 0; i < 8; i++) {
                        int sv = (q0 + i < e1) ? p.src_s[q0 + i] : 0;
                        if ((unsigned)sv >= N_NODES) sv = 0;
                        ss[i] = sv;
                    }
                    #pragma unroll
                    for (int i = 0; i < 8; i++)
                        hv[i] = p.Y[(size_t)ss[i] * 64 + c];
                    #pragma unroll
                    for (int i = 0; i < 8; i++)
                        if (q0 + i < e1) s2 += fmaxf(hv[i] + adv, 0.f);
                }
                p.aggr[(size_t)j * 64 + c] = s2;
            }
        }
        gg.sync();

        // -- Node: h' = relu(Z0 + aggr@Wn1b) @ Wn2 + bn2 --
        {
            unsigned short* n1h = (unsigned short*)arena;
            unsigned short* n1l = (unsigned short*)(arena + 8192);
            unsigned short* n2h = (unsigned short*)(arena + 16384);
            unsigned short* n2l = (unsigned short*)(arena + 24576);
            float* zbuf = (float*)(arena + 32768);  // 4 waves x 16x68 floats
            float* sbn2 = (float*)(arena + 50176);
            stageW64(p.Wn1, offWn1 + 64 * 64, f, n1h, n1l);
            stageW64(p.Wn2, offWn2, f, n2h, n2l);
            if (tid < 64) sbn2[tid] = ldx(p.bn2, offB + tid, f);
            __syncthreads();
            float* zw = zbuf + w * (16 * 68);
            for (int tile = gwave; tile < N_NODES / 16; tile += nwaves) {
                size_t row = (size_t)tile * 16 + m;
                f4v acc[4];
                #pragma unroll
                for (int nt = 0; nt < 4; nt++)
                    #pragma unroll
                    for (int r = 0; r < 4; r++)
                        acc[nt][r] = p.Z0[(size_t)(tile * 16 + quad * 4 + r) * 64 + nt * 16 + m];
                float av[8]; s8v ah, al;
                #pragma unroll
                for (int ks = 0; ks < 2; ks++) {
                    ldrow8(p.aggr, 1, row, ks, quad, av);
                    make_afrag(av, ah, al);
                    mfma3(n1h, n1l, ks, lane, ah, al, acc);
                }
                #pragma unroll
                for (int r = 0; r < 4; r++)
                    #pragma unroll
                    for (int nt = 0; nt < 4; nt++)
                        zw[(quad * 4 + r) * 68 + nt * 16 + m] = fmaxf(acc[nt][r], 0.f);
                // wave-private LDS scratch: no __syncthreads needed
                f4v acc2[4];
                #pragma unroll
                for (int nt = 0; nt < 4; nt++) {
                    float b = sbn2[nt * 16 + m];
                    acc2[nt] = (f4v){b, b, b, b};
                }
                #pragma unroll
                for (int ks = 0; ks < 2; ks++) {
                    #pragma unroll
                    for (int jx = 0; jx < 8; jx++)
                        av[jx] = zw[m * 68 + ks * 32 + quad * 8 + jx];
                    make_afrag(av, ah, al);
                    mfma3(n2h, n2l, ks, lane, ah, al, acc2);
                }
                #pragma unroll
                for (int r = 0; r < 4; r++) {
                    size_t rr = (size_t)(tile * 16 + quad * 4 + r) * 64 + m;
                    #pragma unroll
                    for (int nt = 0; nt < 4; nt++)
                        p.h[rr + nt * 16] = acc2[nt][r];
                }
            }
        }
        gg.sync();
    }

    // ---- pool + head (blocks 0..127) ----
    if (blockIdx.x < N_B) {
        float* red = (float*)arena;  // 4x64
        int b = blockIdx.x;
        int lo = 0, hi = N_NODES;
        while (lo < hi) { int mid = (lo + hi) >> 1; if (p.batch[mid] < b) lo = mid + 1; else hi = mid; }
        int start = lo;
        hi = N_NODES;
        while (lo < hi) { int mid = (lo + hi) >> 1; if (p.batch[mid] < b + 1) lo = mid + 1; else hi = mid; }
        int end = lo;
        float s = 0.f;
        for (int n = start + w; n < end; n += 4)
            s += p.h[(size_t)n * 64 + lane];
        red[w * 64 + lane] = s;
        __syncthreads();
        if (w == 0) {
            float tot = red[lane] + red[64 + lane] + red[128 + lane] + red[192 + lane];
            float c = (float)(end - start);
            float pv = fmaxf(tot / fmaxf(c, 1.0f), 0.f);
            float acc = ldx(p.bo1, lane, f);
            #pragma unroll
            for (int kk = 0; kk < 64; kk++)
                acc += __shfl(pv, kk) * ldx(p.Wo1, kk * 64 + lane, f);
            float t1 = fmaxf(acc, 0.f);
            float acc2 = (lane < OUT_DIM) ? ldx(p.bo2, lane, f) : 0.f;
            #pragma unroll
            for (int kk = 0; kk < 64; kk++) {
                float wv = (lane < OUT_DIM) ? ldx(p.Wo2, kk * OUT_DIM + lane, f) : 0.f;
                acc2 += __shfl(t1, kk) * wv;
            }
            if (lane < OUT_DIM) {
                if (f) ((float*)p.out)[b * OUT_DIM + lane] = acc2;
                else   ((bf16*)p.out)[b * OUT_DIM + lane] = __float2bfloat16(acc2);
            }
        }
    }
}

extern "C" void kernel_launch(void* const* d_in, const int* in_sizes, int n_in,
                              void* d_out, int out_size, void* d_ws, size_t ws_size,
                              hipStream_t stream) {
    const int expect[19] = {
        N_NODES * 64, N_EDGES * 6, N_TRI * 6,
        L_LAYERS * 76 * 64, L_LAYERS * 64,
        L_LAYERS * 128 * 64, L_LAYERS * 64,
        L_LAYERS * 128 * 64, L_LAYERS * 64,
        L_LAYERS * 64 * 64, L_LAYERS * 64,
        64 * 64, 64, 64 * OUT_DIM, OUT_DIM,
        2 * N_EDGES, N_TRI, N_TRI, N_NODES
    };

    char* ws = (char*)d_ws;
    float* h      = (float*)(ws + 0);            // 4,096,000
    float* X      = (float*)(ws + 4096000);      // 4,096,000 (Hh)
    float* Y      = (float*)(ws + 8192000);      // 4,096,000 (Hs)
    float* Z0     = (float*)(ws + 12288000);     // 4,096,000 (h@Wn1a+bn1)
    float* aggr   = (float*)(ws + 16384000);     // 4,096,000
    int*   flag   = (int*)(ws + 20480000);       // 256
    int*   cur_t  = (int*)(ws + 20480256);       // 64,000
    int*   cur_e  = (int*)(ws + 20544256);       // 64,000
    int*   k_srt  = (int*)(ws + 20608256);       // 2,560,000
    int*   src_s  = (int*)(ws + 23168256);       // 1,024,000
    float* cbf_s  = (float*)(ws + 24192256);     // 15,360,000
    const size_t FULL_NEED = 39552256u;

    const int out_n = N_B * OUT_DIM;

    int perm[19];
    bool used[64];
    for (int i = 0; i < 64; i++) used[i] = false;
    int fail_slot = -1;
    for (int i = 0; i < 19; i++) {
        perm[i] = -1;
        for (int jj = 0; jj < n_in && jj < 64; jj++) {
            if (!used[jj] && in_sizes[jj] == expect[i]) { used[jj] = true; perm[i] = jj; break; }
        }
        if (perm[i] < 0 && fail_slot < 0) fail_slot = i;
    }

    if (n_in < 19 || fail_slot >= 0 || ws_size < FULL_NEED) {
        float code = (ws_size < FULL_NEED) ? 40000.0f
                   : (n_in < 19)           ? 50000.0f
                   : 20000.0f + 1000.0f * (float)fail_slot;
        k_probe<<<1, 64, 0, stream>>>(d_in[0], (int*)d_ws);
        k_fill<<<(out_n + 255) / 256, 256, 0, stream>>>(d_out, (int*)d_ws, code, out_n);
        return;
    }

    MP p;
    p.x   = d_in[perm[0]];  p.rbf = d_in[perm[1]];  p.cbf = d_in[perm[2]];
    p.W1  = d_in[perm[3]];  p.b1  = d_in[perm[4]];
    p.W2  = d_in[perm[5]];  p.b2  = d_in[perm[6]];
    p.Wn1 = d_in[perm[7]];  p.bn1 = d_in[perm[8]];
    p.Wn2 = d_in[perm[9]];  p.bn2 = d_in[perm[10]];
    p.Wo1 = d_in[perm[11]]; p.bo1 = d_in[perm[12]];
    p.Wo2 = d_in[perm[13]]; p.bo2 = d_in[perm[14]];
    p.edge_index = (const int*)d_in[perm[15]];
    p.k_idx = (const int*)d_in[perm[16]];
    p.j_idx = (const int*)d_in[perm[17]];
    p.batch = (const int*)d_in[perm[18]];
    p.h = h; p.X = X; p.Y = Y; p.Z0 = Z0; p.aggr = aggr;
    p.flag = flag; p.cur_t = cur_t; p.cur_e = cur_e;
    p.k_srt = k_srt; p.src_s = src_s; p.cbf_s = cbf_s;
    p.out = d_out;

    // grid: as many co-resident blocks as occupancy allows, capped at 512,
    // floor 256 (>=128 needed for pool/head; grid-stride handles any size)
    int nb = 0;
    hipOccupancyMaxActiveBlocksPerMultiprocessor(&nb, k_mega, 256, 0);
    if (nb < 1) nb = 1;
    int grid = nb * 256;
    if (grid > 512) grid = 512;
    if (grid < 256) grid = 256;

    void* args[] = {(void*)&p};
    hipLaunchCooperativeKernel((void*)k_mega, dim3(grid), dim3(256), args, 0, stream);
}

// Round 11
// 412.193 us; speedup vs baseline: 2.3037x; 2.3037x over previous
//
#include <hip/hip_runtime.h>
#include <hip/hip_bf16.h>

// DimeNet-like GNN, f32 in/out (flag=1 confirmed rounds 2-9; ws ~268 MB).
// Round 10: best-known multi-kernel structure + TriEdge latency-chain fix:
//  - sort writes cheap 4B payloads (k_srt, src_s) so tri chain is
//    {tri_o,k_srt streaming} -> {cbf,Hh parallel random} (2 wide levels),
//    edge chain is src_s streaming -> Hs gather (1 level)
//  - tri batch-4 + float2 cbf loads (~60 VGPR, 6-8 waves/SIMD occupancy)
//  - validated fusions kept: lin2out (Hh+Hs), edge_f (Ad shfl-GEMV fused),
//    node_f (both node stages), poolhead. 20 dispatches.

#define N_NODES 16000
#define N_EDGES 256000
#define N_TRI   640000
#define N_B     128
#define OUT_DIM 32
#define L_LAYERS 3

typedef __hip_bfloat16 bf16;
typedef short s8v __attribute__((ext_vector_type(8)));
typedef float f4v __attribute__((ext_vector_type(4)));

__device__ __forceinline__ float ldx(const void* p, size_t i, int f) {
    if (f) return ((const float*)p)[i];
    return __bfloat162float(((const bf16*)p)[i]);
}

__device__ __forceinline__ unsigned short f2bf_rne(float x) {
    unsigned int u = __float_as_uint(x);
    unsigned int r = (u + 0x7FFFu + ((u >> 16) & 1u)) >> 16;
    return (unsigned short)r;
}
__device__ __forceinline__ float bf2f(unsigned short b) {
    return __uint_as_float(((unsigned int)b) << 16);
}
__device__ __forceinline__ void split2(float a, unsigned short& h, unsigned short& l) {
    h = f2bf_rne(a);
    l = f2bf_rne(a - bf2f(h));
}
__device__ __forceinline__ void make_afrag(const float* av, s8v& ah, s8v& al) {
    #pragma unroll
    for (int j = 0; j < 8; j++) {
        unsigned short h, l; split2(av[j], h, l);
        ah[j] = (short)h; al[j] = (short)l;
    }
}

// stage W (64-col, KS K-steps of 32) into split hi/lo fragment order
__device__ __forceinline__ void stageW(const void* W, size_t offW, int KS, int f,
                                       unsigned short* sBhi, unsigned short* sBlo) {
    for (int idx = threadIdx.x; idx < KS * 2048; idx += 256) {
        int jj = idx & 7, ln = (idx >> 3) & 63, nt = (idx >> 9) & 3, ks = idx >> 11;
        int k = ks * 32 + (ln >> 4) * 8 + jj;
        int n = nt * 16 + (ln & 15);
        float w = ldx(W, offW + (size_t)k * 64 + n, f);
        unsigned short h_, l_; split2(w, h_, l_);
        sBhi[idx] = h_; sBlo[idx] = l_;
    }
}

__device__ __forceinline__ void mfma3(const unsigned short* sBhi, const unsigned short* sBlo,
                                      int ks, int lane, const s8v& ah, const s8v& al,
                                      f4v acc[4]) {
    #pragma unroll
    for (int nt = 0; nt < 4; nt++) {
        s8v bh = *(const s8v*)&sBhi[(ks * 4 + nt) * 512 + lane * 8];
        s8v bl = *(const s8v*)&sBlo[(ks * 4 + nt) * 512 + lane * 8];
        acc[nt] = __builtin_amdgcn_mfma_f32_16x16x32_bf16(ah, bh, acc[nt], 0, 0, 0);
        acc[nt] = __builtin_amdgcn_mfma_f32_16x16x32_bf16(al, bh, acc[nt], 0, 0, 0);
        acc[nt] = __builtin_amdgcn_mfma_f32_16x16x32_bf16(ah, bl, acc[nt], 0, 0, 0);
    }
}

__device__ __forceinline__ void ldrow8(const void* A, int fa, size_t row, int ks,
                                       int quad, float av[8]) {
    if (fa) {
        const float* p = (const float*)A + row * 64 + ks * 32 + quad * 8;
        float4 x0 = ((const float4*)p)[0], x1 = ((const float4*)p)[1];
        av[0] = x0.x; av[1] = x0.y; av[2] = x0.z; av[3] = x0.w;
        av[4] = x1.x; av[5] = x1.y; av[6] = x1.z; av[7] = x1.w;
    } else {
        const bf16* p = (const bf16*)A + row * 64 + ks * 32 + quad * 8;
        #pragma unroll
        for (int j = 0; j < 8; j++) av[j] = __bfloat162float(p[j]);
    }
}

// ---------------------------------------------------------------- diag helpers
__global__ void k_probe(const void* __restrict__ rbf, int* __restrict__ flag) {
    if (threadIdx.x == 0 && blockIdx.x == 0) {
        const float* p = (const float*)rbf;
        int good = 0;
        for (int i = 0; i < 256; i++) {
            float v = fabsf(p[i]);
            if (v > 1e-4f && v < 100.0f) good++;
        }
        *flag = (good > 192) ? 1 : 0;
    }
}
__global__ void k_fill(void* __restrict__ out, const int* __restrict__ flag,
                       float val, int n) {
    int i = blockIdx.x * blockDim.x + threadIdx.x;
    if (i < n) {
        if (*flag) ((float*)out)[i] = val;
        else       ((bf16*)out)[i] = __float2bfloat16(val);
    }
}

// ---------------------------------------------------------------- setup: zero cursors + probe
__global__ void k_setup(const void* __restrict__ rbf, int* __restrict__ flag,
                        int* __restrict__ cur) {
    int i = blockIdx.x * blockDim.x + threadIdx.x;
    int stride = gridDim.x * blockDim.x;
    for (; i < 2 * N_NODES; i += stride) cur[i] = 0;
    if (blockIdx.x == 0 && threadIdx.x == 0) {
        const float* p = (const float*)rbf;
        int good = 0;
        for (int q = 0; q < 256; q++) {
            float v = fabsf(p[q]);
            if (v > 1e-4f && v < 100.0f) good++;
        }
        *flag = (good > 192) ? 1 : 0;
    }
}

// ---------------------------------------------------------------- fused histograms
__global__ void k_hist2(const int* __restrict__ j_idx, const int* __restrict__ edge_index,
                        int* __restrict__ cur_t, int* __restrict__ cur_e) {
    const int TB = (N_TRI + 255) / 256;  // 2500
    if ((int)blockIdx.x < TB) {
        int i = blockIdx.x * 256 + threadIdx.x;
        if (i < N_TRI) {
            unsigned j = (unsigned)j_idx[i];
            if (j < N_NODES) atomicAdd(&cur_t[j], 1);
        }
    } else {
        int i = (blockIdx.x - TB) * 256 + threadIdx.x;
        if (i < N_EDGES) {
            unsigned d = (unsigned)edge_index[N_EDGES + i];
            if (d < N_NODES) atomicAdd(&cur_e[d], 1);
        }
    }
}

// ---------------------------------------------------------------- scan (2 arrays)
__global__ __launch_bounds__(256) void k_scan2(int* __restrict__ a, int* __restrict__ b) {
    int* cnt = (blockIdx.x == 0) ? a : b;
    __shared__ int part[256];
    int tid = threadIdx.x;
    const int PER = (N_NODES + 255) / 256;  // 63
    int base = tid * PER;
    int s = 0;
    for (int i = 0; i < PER; i++) {
        int idx = base + i;
        if (idx < N_NODES) s += cnt[idx];
    }
    part[tid] = s;
    __syncthreads();
    for (int d = 1; d < 256; d <<= 1) {
        int v = (tid >= d) ? part[tid - d] : 0;
        __syncthreads();
        part[tid] += v;
        __syncthreads();
    }
    int run = (tid > 0) ? part[tid - 1] : 0;
    for (int i = 0; i < PER; i++) {
        int idx = base + i;
        if (idx < N_NODES) {
            int v = cnt[idx];
            cnt[idx] = run;
            run += v;
        }
    }
}

// ---------------------------------------------------------------- fused scatter (+4B payloads)
__global__ void k_scatter2(const int* __restrict__ j_idx, const int* __restrict__ k_idx,
                           const int* __restrict__ edge_index,
                           int* __restrict__ cur_t, int* __restrict__ cur_e,
                           int* __restrict__ tri_o, int* __restrict__ k_srt,
                           int* __restrict__ src_s) {
    const int TB = (N_TRI + 255) / 256;  // 2500
    if ((int)blockIdx.x < TB) {
        int i = blockIdx.x * 256 + threadIdx.x;
        if (i < N_TRI) {
            unsigned j = (unsigned)j_idx[i];
            if (j < N_NODES) {
                int pos = atomicAdd(&cur_t[j], 1);
                if ((unsigned)pos < (unsigned)N_TRI) {
                    unsigned k = (unsigned)k_idx[i]; if (k >= N_NODES) k = 0;
                    tri_o[pos] = i;
                    k_srt[pos] = (int)k;
                }
            }
        }
    } else {
        int e = (blockIdx.x - TB) * 256 + threadIdx.x;
        if (e < N_EDGES) {
            unsigned d = (unsigned)edge_index[N_EDGES + e];
            if (d < N_NODES) {
                int pos = atomicAdd(&cur_e[d], 1);
                if ((unsigned)pos < (unsigned)N_EDGES) {
                    unsigned s = (unsigned)edge_index[e]; if (s >= N_NODES) s = 0;
                    src_s[pos] = (int)s;
                }
            }
        }
    }
    // after this kernel, cur_t/cur_e hold bucket END offsets
}

// ---------------------------------------------------------------- lin2out: Hh and Hs in one pass
__global__ __launch_bounds__(256) void k_lin2out(
    const void* __restrict__ A1, int a1ws,
    const void* __restrict__ W1, size_t offW1, const void* __restrict__ b1,
    const void* __restrict__ W2, size_t offW2, const void* __restrict__ b2,
    size_t offB, const int* __restrict__ flag,
    float* __restrict__ X, float* __restrict__ Y) {
    __shared__ unsigned short h1[2 * 2048], l1[2 * 2048];
    __shared__ unsigned short h2[2 * 2048], l2[2 * 2048];
    __shared__ float sB1[64], sB2[64];
    int f = *flag;
    int fa = a1ws ? 1 : f;
    stageW(W1, offW1, 2, f, h1, l1);
    stageW(W2, offW2, 2, f, h2, l2);
    if (threadIdx.x < 64) {
        sB1[threadIdx.x] = ldx(b1, offB + threadIdx.x, f);
        sB2[threadIdx.x] = ldx(b2, offB + threadIdx.x, f);
    }
    __syncthreads();
    int lane = threadIdx.x & 63;
    int quad = lane >> 4;
    int m = lane & 15;
    int tile = blockIdx.x * 4 + (threadIdx.x >> 6);  // grid 250 -> 1000 waves = NT
    size_t row = (size_t)tile * 16 + m;
    f4v accH[4], accS[4];
    #pragma unroll
    for (int nt = 0; nt < 4; nt++) {
        float bh = sB1[nt * 16 + m], bs = sB2[nt * 16 + m];
        accH[nt] = (f4v){bh, bh, bh, bh};
        accS[nt] = (f4v){bs, bs, bs, bs};
    }
    float av[8]; s8v ah, al;
    #pragma unroll
    for (int ks = 0; ks < 2; ks++) {
        ldrow8(A1, fa, row, ks, quad, av);
        make_afrag(av, ah, al);
        mfma3(h1, l1, ks, lane, ah, al, accH);
        mfma3(h2, l2, ks, lane, ah, al, accS);
    }
    #pragma unroll
    for (int r = 0; r < 4; r++) {
        size_t rr = (size_t)(tile * 16 + quad * 4 + r) * 64 + m;
        #pragma unroll
        for (int nt = 0; nt < 4; nt++) {
            X[rr + nt * 16] = accH[nt][r];
            Y[rr + nt * 16] = accS[nt][r];
        }
    }
}

// ---------------------------------------------------------------- triplet segment sum
// wave per node j: agg_e[j] = sum_p relu(Hh[k_srt[p]] + rbf[j]@W1r + cbf[tri_o[p]]@W1c)
// batch-4, low VGPR; tri_o/k_srt are STREAMING, cbf/Hh random but parallel.
__global__ __launch_bounds__(256) void k_tri_seg(
    const int* __restrict__ ends, const int* __restrict__ tri_o,
    const int* __restrict__ k_srt, const float* __restrict__ Hh,
    const void* __restrict__ rbf, const void* __restrict__ cbf,
    const void* __restrict__ W1, size_t offW,
    const int* __restrict__ flag, float* __restrict__ agg_e) {
    int f = *flag;
    int c = threadIdx.x & 63;
    float wr[6], wc[6];
    #pragma unroll
    for (int q = 0; q < 6; q++) {
        wr[q] = ldx(W1, offW + (size_t)(64 + q) * 64 + c, f);
        wc[q] = ldx(W1, offW + (size_t)(70 + q) * 64 + c, f);
    }
    int j = blockIdx.x * 4 + (threadIdx.x >> 6);  // grid 4000 = exactly N waves
    int p0 = (j == 0) ? 0 : ends[j - 1];
    int p1 = ends[j];
    if (p0 < 0) p0 = 0; if (p0 > N_TRI) p0 = N_TRI;
    if (p1 < p0) p1 = p0; if (p1 > N_TRI) p1 = N_TRI;
    float rb = 0.f;
    #pragma unroll
    for (int q = 0; q < 6; q++)
        rb += ldx(rbf, (size_t)j * 6 + q, f) * wr[q];
    float s = 0.f;
    for (int p = p0; p < p1; p += 4) {
        int tq[4], kq[4];
        float hv[4], cb[4][6];
        #pragma unroll
        for (int i = 0; i < 4; i++) {
            int ok = (p + i < p1);
            int t = ok ? tri_o[p + i] : -1;
            if ((unsigned)t >= N_TRI) t = -1;
            tq[i] = t;
            int k = ok ? k_srt[p + i] : 0;
            if ((unsigned)k >= N_NODES) k = 0;
            kq[i] = k;
        }
        #pragma unroll
        for (int i = 0; i < 4; i++)
            hv[i] = Hh[(size_t)kq[i] * 64 + c];
        #pragma unroll
        for (int i = 0; i < 4; i++) {
            if (tq[i] >= 0) {
                if (f) {
                    const float2* cp = (const float2*)((const float*)cbf + (size_t)tq[i] * 6);
                    float2 c0 = cp[0], c1 = cp[1], c2 = cp[2];
                    cb[i][0] = c0.x; cb[i][1] = c0.y; cb[i][2] = c1.x;
                    cb[i][3] = c1.y; cb[i][4] = c2.x; cb[i][5] = c2.y;
                } else {
                    #pragma unroll
                    for (int q = 0; q < 6; q++)
                        cb[i][q] = ldx(cbf, (size_t)tq[i] * 6 + q, 0);
                }
            }
        }
        #pragma unroll
        for (int i = 0; i < 4; i++) {
            if (tq[i] < 0) continue;
            float v = hv[i] + rb;
            #pragma unroll
            for (int q = 0; q < 6; q++)
                v += cb[i][q] * wc[q];
            s += fmaxf(v, 0.f);
        }
    }
    agg_e[(size_t)j * 64 + c] = s;
}

// ---------------------------------------------------------------- edge segment sum + fused Ad
__global__ __launch_bounds__(256) void k_edge_f(
    const int* __restrict__ ends, const int* __restrict__ src_s,
    const float* __restrict__ Hs, const float* __restrict__ agg_e,
    const void* __restrict__ W2, size_t offW2a, const int* __restrict__ flag,
    float* __restrict__ aggr) {
    __shared__ float sW[64 * 64];
    int f = *flag;
    for (int idx = threadIdx.x; idx < 4096; idx += 256)
        sW[idx] = ldx(W2, offW2a + idx, f);
    __syncthreads();
    int c = threadIdx.x & 63;
    int d = blockIdx.x * 4 + (threadIdx.x >> 6);  // grid 4000 = exactly N waves
    int p0 = (d == 0) ? 0 : ends[d - 1];
    int p1 = ends[d];
    if (p0 < 0) p0 = 0; if (p0 > N_EDGES) p0 = N_EDGES;
    if (p1 < p0) p1 = p0; if (p1 > N_EDGES) p1 = N_EDGES;
    float av = agg_e[(size_t)d * 64 + c];
    float ad = 0.f;
    #pragma unroll
    for (int k = 0; k < 64; k++)
        ad += __shfl(av, k) * sW[k * 64 + c];
    float s = 0.f;
    for (int p = p0; p < p1; p += 8) {
        int ss[8];
        float hv[8];
        #pragma unroll
        for (int i = 0; i < 8; i++) {
            int sv = (p + i < p1) ? src_s[p + i] : 0;
            if ((unsigned)sv >= N_NODES) sv = 0;
            ss[i] = sv;
        }
        #pragma unroll
        for (int i = 0; i < 8; i++)
            hv[i] = Hs[(size_t)ss[i] * 64 + c];
        #pragma unroll
        for (int i = 0; i < 8; i++)
            if (p + i < p1) s += fmaxf(hv[i] + ad, 0.f);
    }
    aggr[(size_t)d * 64 + c] = s;
}

// ---------------------------------------------------------------- fused node MLP
__global__ __launch_bounds__(256) void k_node_f(
    const void* __restrict__ A1, int a1ws, const float* __restrict__ aggr,
    const void* __restrict__ Wn1, const void* __restrict__ bn1,
    const void* __restrict__ Wn2, const void* __restrict__ bn2,
    size_t offW1, size_t offB, size_t offW2,
    const int* __restrict__ flag, float* __restrict__ hout) {
    __shared__ unsigned short s1h[4 * 2048], s1l[4 * 2048];
    __shared__ unsigned short s2h[2 * 2048], s2l[2 * 2048];
    __shared__ float sB1[64], sB2[64];
    __shared__ float zbuf[4][16 * 68];
    int f = *flag;
    int fa = a1ws ? 1 : f;
    stageW(Wn1, offW1, 4, f, s1h, s1l);
    stageW(Wn2, offW2, 2, f, s2h, s2l);
    if (threadIdx.x < 64) {
        sB1[threadIdx.x] = ldx(bn1, offB + threadIdx.x, f);
        sB2[threadIdx.x] = ldx(bn2, offB + threadIdx.x, f);
    }
    __syncthreads();
    int lane = threadIdx.x & 63;
    int quad = lane >> 4;
    int m = lane & 15;
    int w = threadIdx.x >> 6;
    int tile = blockIdx.x * 4 + w;  // grid 250 -> one tile per wave
    size_t row = (size_t)tile * 16 + m;
    f4v acc[4];
    #pragma unroll
    for (int nt = 0; nt < 4; nt++) {
        float b = sB1[nt * 16 + m];
        acc[nt] = (f4v){b, b, b, b};
    }
    float av[8]; s8v ah, al;
    #pragma unroll
    for (int ks = 0; ks < 2; ks++) {
        ldrow8(A1, fa, row, ks, quad, av);
        make_afrag(av, ah, al);
        mfma3(s1h, s1l, ks, lane, ah, al, acc);
    }
    #pragma unroll
    for (int ks = 0; ks < 2; ks++) {
        ldrow8(aggr, 1, row, ks, quad, av);
        make_afrag(av, ah, al);
        mfma3(s1h, s1l, 2 + ks, lane, ah, al, acc);
    }
    #pragma unroll
    for (int r = 0; r < 4; r++)
        #pragma unroll
        for (int nt = 0; nt < 4; nt++)
            zbuf[w][(quad * 4 + r) * 68 + nt * 16 + m] = fmaxf(acc[nt][r], 0.f);
    // wave-private LDS scratch: no block sync needed
    f4v acc2[4];
    #pragma unroll
    for (int nt = 0; nt < 4; nt++) {
        float b = sB2[nt * 16 + m];
        acc2[nt] = (f4v){b, b, b, b};
    }
    #pragma unroll
    for (int ks = 0; ks < 2; ks++) {
        #pragma unroll
        for (int jx = 0; jx < 8; jx++)
            av[jx] = zbuf[w][m * 68 + ks * 32 + quad * 8 + jx];
        make_afrag(av, ah, al);
        mfma3(s2h, s2l, ks, lane, ah, al, acc2);
    }
    #pragma unroll
    for (int r = 0; r < 4; r++) {
        size_t rr = (size_t)(tile * 16 + quad * 4 + r) * 64 + m;
        #pragma unroll
        for (int nt = 0; nt < 4; nt++)
            hout[rr + nt * 16] = acc2[nt][r];
    }
}

// ---------------------------------------------------------------- fused pool + head
__global__ __launch_bounds__(256) void k_poolhead(
    const float* __restrict__ h, const int* __restrict__ batch,
    const void* __restrict__ Wo1, const void* __restrict__ bo1,
    const void* __restrict__ Wo2, const void* __restrict__ bo2,
    const int* __restrict__ flag, void* __restrict__ out) {
    __shared__ float red[4][64];
    int b = blockIdx.x;
    int lo = 0, hi = N_NODES;
    while (lo < hi) { int mid = (lo + hi) >> 1; if (batch[mid] < b) lo = mid + 1; else hi = mid; }
    int start = lo;
    hi = N_NODES;
    while (lo < hi) { int mid = (lo + hi) >> 1; if (batch[mid] < b + 1) lo = mid + 1; else hi = mid; }
    int end = lo;
    int lane = threadIdx.x & 63;
    int w = threadIdx.x >> 6;
    float s = 0.f;
    for (int n = start + w; n < end; n += 4)
        s += h[(size_t)n * 64 + lane];
    red[w][lane] = s;
    __syncthreads();
    if (w == 0) {
        int f = *flag;
        float tot = red[0][lane] + red[1][lane] + red[2][lane] + red[3][lane];
        float c = (float)(end - start);
        float p = fmaxf(tot / fmaxf(c, 1.0f), 0.f);
        float acc = ldx(bo1, lane, f);
        #pragma unroll
        for (int kk = 0; kk < 64; kk++)
            acc += __shfl(p, kk) * ldx(Wo1, kk * 64 + lane, f);
        float t1 = fmaxf(acc, 0.f);
        float acc2 = (lane < OUT_DIM) ? ldx(bo2, lane, f) : 0.f;
        #pragma unroll
        for (int kk = 0; kk < 64; kk++) {
            float wv = (lane < OUT_DIM) ? ldx(Wo2, kk * OUT_DIM + lane, f) : 0.f;
            acc2 += __shfl(t1, kk) * wv;
        }
        if (lane < OUT_DIM) {
            if (f) ((float*)out)[b * OUT_DIM + lane] = acc2;
            else   ((bf16*)out)[b * OUT_DIM + lane] = __float2bfloat16(acc2);
        }
    }
}

extern "C" void kernel_launch(void* const* d_in, const int* in_sizes, int n_in,
                              void* d_out, int out_size, void* d_ws, size_t ws_size,
                              hipStream_t stream) {
    const int expect[19] = {
        N_NODES * 64, N_EDGES * 6, N_TRI * 6,
        L_LAYERS * 76 * 64, L_LAYERS * 64,
        L_LAYERS * 128 * 64, L_LAYERS * 64,
        L_LAYERS * 128 * 64, L_LAYERS * 64,
        L_LAYERS * 64 * 64, L_LAYERS * 64,
        64 * 64, 64, 64 * OUT_DIM, OUT_DIM,
        2 * N_EDGES, N_TRI, N_TRI, N_NODES
    };

    char* ws = (char*)d_ws;
    float* h      = (float*)(ws + 0);            // 4,096,000
    float* agg_e  = (float*)(ws + 4096000);      // 4,096,000
    float* aggr   = (float*)(ws + 8192000);      // 4,096,000
    float* X      = (float*)(ws + 12288000);     // 4,096,000 (Hh)
    float* Y      = (float*)(ws + 16384000);     // 4,096,000 (Hs)
    int*   flag   = (int*)(ws + 20480000);       // 256
    int*   cur_t  = (int*)(ws + 20480256);       // 64,000
    int*   cur_e  = (int*)(ws + 20544256);       // 64,000
    int*   tri_o  = (int*)(ws + 20608256);       // 2,560,000
    int*   k_srt  = (int*)(ws + 23168256);       // 2,560,000
    int*   src_s  = (int*)(ws + 25728256);       // 1,024,000
    const size_t FULL_NEED = 26752256u;

    const int out_n = N_B * OUT_DIM;

    int perm[19];
    bool used[64];
    for (int i = 0; i < 64; i++) used[i] = false;
    int fail_slot = -1;
    for (int i = 0; i < 19; i++) {
        perm[i] = -1;
        for (int jj = 0; jj < n_in && jj < 64; jj++) {
            if (!used[jj] && in_sizes[jj] == expect[i]) { used[jj] = true; perm[i] = jj; break; }
        }
        if (perm[i] < 0 && fail_slot < 0) fail_slot = i;
    }

    if (n_in < 19 || fail_slot >= 0 || ws_size < FULL_NEED) {
        float code = (ws_size < FULL_NEED) ? 40000.0f
                   : (n_in < 19)           ? 50000.0f
                   : 20000.0f + 1000.0f * (float)fail_slot;
        k_probe<<<1, 64, 0, stream>>>(d_in[0], (int*)d_ws);
        k_fill<<<(out_n + 255) / 256, 256, 0, stream>>>(d_out, (int*)d_ws, code, out_n);
        return;
    }

    const void* x    = d_in[perm[0]];
    const void* rbf  = d_in[perm[1]];
    const void* cbf  = d_in[perm[2]];
    const void* W1   = d_in[perm[3]];
    const void* b1   = d_in[perm[4]];
    const void* W2   = d_in[perm[5]];
    const void* b2   = d_in[perm[6]];
    const void* Wn1  = d_in[perm[7]];
    const void* bn1  = d_in[perm[8]];
    const void* Wn2  = d_in[perm[9]];
    const void* bn2  = d_in[perm[10]];
    const void* Wo1  = d_in[perm[11]];
    const void* bo1  = d_in[perm[12]];
    const void* Wo2  = d_in[perm[13]];
    const void* bo2  = d_in[perm[14]];
    const int* edge_index = (const int*)d_in[perm[15]];
    const int* k_idx = (const int*)d_in[perm[16]];
    const int* j_idx = (const int*)d_in[perm[17]];
    const int* batch = (const int*)d_in[perm[18]];

    const int TB = (N_TRI + 255) / 256;    // 2500
    const int EB = (N_EDGES + 255) / 256;  // 1000

    k_setup<<<64, 256, 0, stream>>>(rbf, flag, cur_t);
    k_hist2<<<TB + EB, 256, 0, stream>>>(j_idx, edge_index, cur_t, cur_e);
    k_scan2<<<2, 256, 0, stream>>>(cur_t, cur_e);
    k_scatter2<<<TB + EB, 256, 0, stream>>>(j_idx, k_idx, edge_index,
                                            cur_t, cur_e, tri_o, k_srt, src_s);

    const void* hc = x;  // layer 0 reads x directly
    int hws = 0;
    for (int l = 0; l < L_LAYERS; l++) {
        size_t offW1l = (size_t)l * 76 * 64;
        size_t offW2l = (size_t)l * 128 * 64;
        size_t offWn2 = (size_t)l * 64 * 64;
        size_t offB   = (size_t)l * 64;
        // Hh -> X, Hs -> Y (one pass over h)
        k_lin2out<<<250, 256, 0, stream>>>(hc, hws, W1, offW1l, b1,
                                           W2, offW2l, b2, offB, flag, X, Y);
        // agg_e = segsum_j relu(Hh[k] + rbf[j]@W1r + cbf[t]@W1c)
        k_tri_seg<<<4000, 256, 0, stream>>>(cur_t, tri_o, k_srt, X, rbf, cbf,
                                            W1, offW1l, flag, agg_e);
        // aggr = segsum_d relu(Hs[src] + (agg_e[d] @ W2a))
        k_edge_f<<<4000, 256, 0, stream>>>(cur_e, src_s, Y, agg_e,
                                           W2, offW2l + 64 * 64, flag, aggr);
        // h' = relu([h|aggr]@Wn1+bn1)@Wn2+bn2
        k_node_f<<<250, 256, 0, stream>>>(hc, hws, aggr, Wn1, bn1, Wn2, bn2,
                                          offW2l, offB, offWn2, flag, h);
        hc = h; hws = 1;
    }
    k_poolhead<<<N_B, 256, 0, stream>>>(h, batch, Wo1, bo1, Wo2, bo2, flag, d_out);
}